// Round 14
// baseline (440.095 us; speedup 1.0000x reference)
//
#include <hip/hip_runtime.h>
#include <math.h>

#define B     64
#define NCAP  64
#define LV    197
#define LT    32
#define C     512
#define NSP   196
#define NKEEP 98
#define HID   102
#define KEEPED 49

// Workspace layout (float element offsets). Total ~79.7 MB (< proven 106.8 MB).
#define OFF_ATTNX   12608                     // B*NSP
#define OFF_WSMAT   25152                     // B*NSP*KEEPED
#define OFF_WT      639808                    // u16 2*512*512 (bf16 wi2t^T / wt2i^T)
#define OFF_GLOT    1688384                   // C*NCAP
#define OFF_ATTNYT  1721152                   // 4096*196 floats (transposed [b][i][s])
#define OFF_IMGT    14164800                  // u16 64*7*32*512 fragment-major imgT
#define OFF_QBB     17834816                  // u16 64*6*16*512 fragment-major Qbb
#define OFF_QCAP    19407680                  // u16 64*32*512 row-major cap rows (qproj input)

typedef unsigned int u32;
typedef unsigned short u16;
typedef __bf16 bf16x8 __attribute__((ext_vector_type(8)));
typedef float f32x4 __attribute__((ext_vector_type(4)));
typedef unsigned int uint4v __attribute__((ext_vector_type(4)));

__device__ __forceinline__ u16 f2bf(float f) {
    u32 u = __builtin_bit_cast(u32, f);
    return (u16)((u + 0x7FFFu + ((u >> 16) & 1u)) >> 16);
}
__device__ __forceinline__ bf16x8 ld_bf8(const u16* p) {
    uint4v v = *reinterpret_cast<const uint4v*>(p);
    return __builtin_bit_cast(bf16x8, v);
}

__device__ __forceinline__ float gelu_exact(float x) {
    return 0.5f * x * (1.f + erff(x * 0.70710678118654752f));
}

// ---------------------------------------------------------------- k_pre (2496 blocks, 512 thr):
// imgt-frag (0..511) | cap_norm (512..767) | wt (768..895) | img_row (896..2495)
// NOTE: attn_y must NOT live here — it reads gloT written by cap_norm blocks (cross-block
// dependency within a launch is a race; learned the hard way in round 13).
__global__ __launch_bounds__(512) void k_pre(const float* __restrict__ img,
                                             const float* __restrict__ cap,
                                             const float* __restrict__ wi2t,
                                             const float* __restrict__ wt2i,
                                             const float* __restrict__ gamw,
                                             const float* __restrict__ betw,
                                             const float* __restrict__ w1,
                                             const float* __restrict__ b1,
                                             const float* __restrict__ w2,
                                             const float* __restrict__ b2,
                                             const float* __restrict__ scale_p,
                                             u16* __restrict__ imgTf,
                                             float* __restrict__ gloT,
                                             u16* __restrict__ Qbbf,
                                             u16* __restrict__ Qcap,
                                             u16* __restrict__ wT,
                                             float* __restrict__ attn_x,
                                             float* __restrict__ WsM) {
    int idx = blockIdx.x, t = threadIdx.x;
    __shared__ __align__(16) u16 shbu[64 * 224];    // 28 KB union
    float* shm = (float*)shbu;

    if (idx < 512) {
        // ---- imgT fragment-major: tile (ks, ct) holds 1KB: value[lane*8+j] =
        //      bf16(img[b][s = ks*32 + (lane>>4)*8 + j][c = ct*16 + (lane&15)])
        int b = idx >> 3, cg = idx & 7;
        for (int f = t; f < 64 * 27; f += 512) shbu[(f / 27) * 224 + 197 + (f % 27)] = 0;
        int cc = t & 63;
        for (int sb = t >> 6; sb < 197; sb += 8) {
            float v = img[((size_t)b * LV + sb) * C + cg * 64 + cc];
            shbu[cc * 224 + sb] = f2bf(v);
        }
        __syncthreads();
        const u32* Tu = (const u32*)shbu;
        u32* outp = (u32*)imgTf + (size_t)b * 7 * 32 * 256;
        for (int f = t; f < 7 * 4 * 256; f += 512) {
            int ks = f >> 10, rem = f & 1023;
            int ctl = rem >> 8, g = rem & 255;
            int lane_o = g >> 2, j2 = g & 3;
            int quad_o = lane_o >> 4, l15_o = lane_o & 15;
            int ccl = ctl * 16 + l15_o;
            int s = ks * 32 + quad_o * 8 + 2 * j2;
            u32 v = Tu[ccl * 112 + (s >> 1)];
            outp[(size_t)(ks * 32 + cg * 4 + ctl) * 256 + g] = v;
        }
    } else if (idx < 768) {
        // ---- caption norms, 8 rows/block (wave wv owns row tg*8+wv)
        int e = idx - 512, i = e >> 2, tg = e & 3;
        int lane = t & 63, wv = t >> 6;
        int tt = tg * 8 + wv;
        const float* row = cap + ((size_t)i * LT + tt) * C;
        float v[8]; float ss = 0.f;
#pragma unroll
        for (int q = 0; q < 8; ++q) { v[q] = row[lane + 64 * q]; ss += v[q] * v[q]; }
        for (int o = 32; o > 0; o >>= 1) ss += __shfl_down(ss, o);
        ss = __shfl(ss, 0);
        float inv = 1.f / fmaxf(sqrtf(ss), 1e-12f);
        u16* qrow = Qcap + ((size_t)i * 32 + tt) * C;
        int mi = tt >> 4, l15f = tt & 15;
        u16* qfb = Qbbf + (size_t)(i * 6 + mi) * 16 * 512;
#pragma unroll
        for (int q = 0; q < 8; ++q) {
            float n = v[q] * inv;
            u16 nb = f2bf(n);
            int c = lane + 64 * q;
            qrow[c] = nb;
            int ks = c >> 5, quadf = (c >> 3) & 3, jf = c & 7;
            qfb[(size_t)ks * 512 + (quadf * 16 + l15f) * 8 + jf] = nb;
            if (tt == 0) gloT[c * NCAP + i] = n;
        }
    } else if (idx < 896) {
        // ---- transpose wi2t/wt2i -> bf16 [j][c], one 64x64 tile per block
        int e = idx - 768;
        int mat = e >> 6, ty = e & 63, jg = ty >> 3, cg = ty & 7;
        const float* W = mat ? wt2i : wi2t;
        u16 (*tile)[65] = (u16(*)[65])shbu;
        for (int f = t; f < 4096; f += 512) {
            int cc2 = f >> 6, jj = f & 63;
            tile[jj][cc2] = f2bf(W[(size_t)(cg * 64 + cc2) * 512 + jg * 64 + jj]);
        }
        __syncthreads();
        for (int f = t; f < 4096; f += 512) {
            int jj = f >> 6, cc2 = f & 63;
            wT[((size_t)mat * 512 + jg * 64 + jj) * 512 + cg * 64 + cc2] = tile[jj][cc2];
        }
    } else {
        // ---- LN -> w1 -> gelu -> w2 + attn_x, 8 rows/block
        int e = idx - 896;
        int b = e / 25, sg = e - b * 25;
        int s0 = sg * 8;
        int R = NSP - s0; if (R > 8) R = 8;
        float (*lnr)[C]   = (float(*)[C])shm;
        float (*HH)[104]  = (float(*)[104])(shm + 4096);
        float (*redm)[4]  = (float(*)[4])(shm + 4928);

        int g = t >> 6, lane = t & 63;
        if (g < R) {
            const float* row = img + ((size_t)b * LV + 1 + s0 + g) * C;
            const float* cls = img + (size_t)b * LV * C;
            float sm = 0.f, ss = 0.f, dd = 0.f, sc = 0.f;
            for (int c = lane; c < C; c += 64) {
                float v = row[c];
                float cv = cls[c];
                sm += v; ss += v * v; dd += v * cv; sc += cv * cv;
                lnr[g][c] = v;
            }
            for (int o = 32; o > 0; o >>= 1) {
                sm += __shfl_down(sm, o);
                ss += __shfl_down(ss, o);
                dd += __shfl_down(dd, o);
                sc += __shfl_down(sc, o);
            }
            if (lane == 0) { redm[g][0] = sm; redm[g][1] = ss; redm[g][2] = dd; redm[g][3] = sc; }
        }
        __syncthreads();
        for (int f = t; f < R * C; f += 512) {
            int rr = f >> 9, c = f & 511;
            float mean = redm[rr][0] * (1.f / C);
            float var  = redm[rr][1] * (1.f / C) - mean * mean;
            float rstd = 1.f / sqrtf(var + 1e-5f);
            lnr[rr][c] = (lnr[rr][c] - mean) * rstd * gamw[c] + betw[c];
        }
        if (t < R) {
            float inv0 = 1.f / fmaxf(sqrtf(redm[t][3]), 1e-12f);
            float invs = 1.f / fmaxf(sqrtf(redm[t][1]), 1e-12f);
            attn_x[b * NSP + s0 + t] = redm[t][2] * inv0 * invs;
        }
        __syncthreads();
        if (t < 408) {
            int rr2 = t / 102;
            int j = t - rr2 * 102;
            int rw0 = rr2 * 2, rw1 = rr2 * 2 + 1;
            float a0 = b1[j], a1 = b1[j];
            for (int c = 0; c < C; ++c) {
                float wv = w1[c * HID + j];
                a0 += lnr[rw0][c] * wv;
                a1 += lnr[rw1][c] * wv;
            }
            if (rw0 < R) HH[rw0][j] = gelu_exact(a0);
            if (rw1 < R) HH[rw1][j] = gelu_exact(a1);
        }
        __syncthreads();
        float scale = scale_p[0];
        if (t < 392) {
            int k = t % 49, rh = t / 49;
            if (rh < R) {
                float a = b2[k];
                for (int h = 0; h < HID; ++h) a += HH[rh][h] * w2[h * 49 + k];
                WsM[((size_t)b * NSP + s0 + rh) * 49 + k] = a * scale;
            }
        }
    }
}

// ---------------------------------------------------------------- k_mid2 (1856 blocks, 512 thr):
// qproj (0..255) | attn_y (256..1855). Both read only k_pre outputs + inputs; disjoint writes.
__global__ __launch_bounds__(512) void k_mid2(const float* __restrict__ img,
                                              const u16* __restrict__ wT,
                                              const float* __restrict__ bi2t,
                                              const float* __restrict__ bt2i,
                                              const u16* __restrict__ Qcap,
                                              u16* __restrict__ Qbbf,
                                              const float* __restrict__ gloT,
                                              float* __restrict__ attn_yT) {
    int idx = blockIdx.x, t = threadIdx.x;
    __shared__ __align__(16) float shm[4160];

    if (idx < 256) {
        // ---- qi2t/qt2i via MFMA (A/B prefetch); output into fragment-major Qbbf
        int i = idx & 63, p = idx >> 6;
        int lane = t & 63, wu = t >> 6;
        int l15 = lane & 15, quad = lane >> 4;
        int mat = wu >> 2;
        int miq = (wu >> 1) & 1;
        int nh  = wu & 1;
        int ni0 = p * 8 + nh * 4;
        const u16* Arow = Qcap + ((size_t)i * 32 + miq * 16 + l15) * 512;
        const u16* Wm   = wT + (size_t)mat * 512 * 512;
        f32x4 acc[4];
#pragma unroll
        for (int n = 0; n < 4; ++n) acc[n] = (f32x4){0.f, 0.f, 0.f, 0.f};
        bf16x8 A = ld_bf8(Arow + quad * 8);
        bf16x8 Bf[4];
#pragma unroll
        for (int n = 0; n < 4; ++n)
            Bf[n] = ld_bf8(Wm + (size_t)((ni0 + n) * 16 + l15) * 512 + quad * 8);
        for (int ks = 0; ks < 16; ++ks) {
            bf16x8 An; bf16x8 Bn[4];
            if (ks < 15) {
                An = ld_bf8(Arow + (ks + 1) * 32 + quad * 8);
#pragma unroll
                for (int n = 0; n < 4; ++n)
                    Bn[n] = ld_bf8(Wm + (size_t)((ni0 + n) * 16 + l15) * 512 + (ks + 1) * 32 + quad * 8);
            }
#pragma unroll
            for (int n = 0; n < 4; ++n)
                acc[n] = __builtin_amdgcn_mfma_f32_16x16x32_bf16(A, Bf[n], acc[n], 0, 0, 0);
            A = An;
#pragma unroll
            for (int n = 0; n < 4; ++n) Bf[n] = Bn[n];
        }
        const float* bias = mat ? bt2i : bi2t;
#pragma unroll
        for (int n = 0; n < 4; ++n) {
            int j = (ni0 + n) * 16 + l15;
            float bj = bias[j];
            int ksf = j >> 5, quadf = (j >> 3) & 3, jf = j & 7;
#pragma unroll
            for (int r = 0; r < 4; ++r) {
                int q = 32 + mat * 32 + miq * 16 + quad * 4 + r;
                int mi = q >> 4, l15f = q & 15;
                Qbbf[(size_t)((i * 6 + mi) * 16 + ksf) * 512 + (quadf * 16 + l15f) * 8 + jf]
                    = f2bf(acc[n][r] + bj);
            }
        }
    } else {
        // ---- attn_y transposed, 8 rows/block, wave w owns row w
        int e = idx - 256;
        int b = e / 25;
        int s0 = (e - b * 25) * 8;
        int R = NSP - s0; if (R > 8) R = 8;
        float (*xr)[C] = (float(*)[C])shm;
        float* rnorm = shm + 4096;

        for (int f = t; f < R * C; f += 512) {
            int rr = f >> 9, c = f & 511;
            xr[rr][c] = img[((size_t)b * LV + 1 + s0 + rr) * C + c];
        }
        __syncthreads();
        {
            int row = t >> 6, l = t & 63;
            if (row < R) {
                float ss = 0.f;
                for (int c = l; c < C; c += 64) { float v = xr[row][c]; ss += v * v; }
                for (int o = 32; o > 0; o >>= 1) ss += __shfl_down(ss, o);
                if (l == 0) rnorm[row] = 1.f / fmaxf(sqrtf(ss), 1e-12f);
            }
        }
        __syncthreads();
        for (int f = t; f < R * C; f += 512) {
            int rr = f >> 9, c = f & 511;
            xr[rr][c] *= rnorm[rr];
        }
        __syncthreads();
        int i = t & 63, w = t >> 6;
        if (w < R) {
            float a0 = 0.f;
            for (int c4 = 0; c4 < C / 4; ++c4) {
                float g0 = gloT[(c4 * 4 + 0) * NCAP + i];
                float g1 = gloT[(c4 * 4 + 1) * NCAP + i];
                float g2 = gloT[(c4 * 4 + 2) * NCAP + i];
                float g3 = gloT[(c4 * 4 + 3) * NCAP + i];
                float4 x0 = ((const float4*)xr[w])[c4];
                a0 += x0.x * g0 + x0.y * g1 + x0.z * g2 + x0.w * g3;
            }
            attn_yT[((size_t)b * NCAP + i) * NSP + s0 + w] = a0;
        }
    }
}

// ---------------------------------------------------------------- main per-pair kernel: rank + two MFMA GEMMs
__global__ __launch_bounds__(512, 4) void k_main(const float* __restrict__ attn_x,
                                                 const float* __restrict__ attn_yT,
                                                 const float* __restrict__ WsM,
                                                 const u16* __restrict__ imgTf,
                                                 const u16* __restrict__ Qbbf,
                                                 const float* __restrict__ temp_p,
                                                 float* __restrict__ out) {
    int lin = blockIdx.x + NCAP * blockIdx.y;     // XCD swizzle: lin%8 selects b-octet
    int b = (lin & 7) * 8 + ((lin >> 3) & 7);
    int i = lin >> 6;
    int t = threadIdx.x;
    int lane = t & 63, wu = t >> 6;
    int l15 = lane & 15, quad = lane >> 4;

    __shared__ __align__(16) u16 TnBuf[51 * 520];   // aliases Pf(51x232) then ULDS(96x52 f32)
    __shared__ float rowsq[8][64];
    __shared__ float invn[64];
    __shared__ float colM[51], colZ[51], rowM[32], rowZ[32], redw[8];
    __shared__ float scoreS[NSP];
    __shared__ int   keepL[NKEEP];
    __shared__ int   nonL[NKEEP];
    __shared__ float snon[NKEEP];
    __shared__ short rnkH[2][NSP];

    u16*   Pf   = TnBuf;
    float* ULDS = (float*)TnBuf;

    // ---- 1. zero Pf rows 0..50 (16B stores) + load scores
    {
        uint4v* Pfv = (uint4v*)Pf;
        for (int f = t; f < 51 * 232 / 8; f += 512) Pfv[f] = (uint4v){0, 0, 0, 0};
    }
    if (t < NSP)
        scoreS[t] = attn_x[b * NSP + t] + attn_yT[((size_t)b * NCAP + i) * NSP + t];
    __syncthreads();
    // ---- 2. stable-descending rank, split over 392 threads
    if (t < 2 * NSP) {
        int half = (t >= NSP) ? 1 : 0;
        int s = t - half * NSP;
        float sv = scoreS[s];
        int u0 = half * 98, u1 = half ? NSP : 98;
        int r = 0;
        for (int u = u0; u < u1; ++u) {
            float o = scoreS[u];
            r += (o > sv) || (o == sv && u < s);
        }
        rnkH[half][s] = (short)r;
    }
    __syncthreads();
    if (t < NSP) {
        int r = rnkH[0][t] + rnkH[1][t];
        if (r < NKEEP) keepL[r] = t;
        else { nonL[r - NKEEP] = t; snon[r - NKEEP] = scoreS[t]; }
    }
    __syncthreads();
    // ---- 3. scatter P into Pf
    if (t == 0) Pf[0] = 0x3F80;                       // cls one-hot (1.0)
    for (int f = t; f < NKEEP * KEEPED; f += 512) {
        int j = f / KEEPED, k = f - j * KEEPED;
        int s = keepL[j];
        Pf[(1 + k) * 232 + 1 + s] = f2bf(expf(WsM[((size_t)b * NSP + s) * KEEPED + k]));
    }
    if (t < NKEEP) Pf[50 * 232 + 1 + nonL[t]] = f2bf(expf(snon[t]));
    __syncthreads();

    // ---- phase 1: T(51x512) = Pfull @ imgT ; wave w owns ct range [4w, 4w+4)
    const u16* imgTb = imgTf + (size_t)b * 7 * 32 * 512;
    f32x4 acc[4][4];
#pragma unroll
    for (int mi = 0; mi < 4; ++mi)
#pragma unroll
        for (int nj = 0; nj < 4; ++nj) acc[mi][nj] = (f32x4){0.f, 0.f, 0.f, 0.f};

    for (int ks = 0; ks < 7; ++ks) {
        bf16x8 Afr[4];
#pragma unroll
        for (int mi = 0; mi < 4; ++mi)
            Afr[mi] = ld_bf8(Pf + (mi * 16 + l15) * 232 + ks * 32 + quad * 8);
#pragma unroll
        for (int nj = 0; nj < 4; ++nj) {
            bf16x8 Bf = ld_bf8(imgTb + (size_t)(ks * 32 + wu * 4 + nj) * 512 + lane * 8);
#pragma unroll
            for (int mi = 0; mi < 4; ++mi)
                acc[mi][nj] = __builtin_amdgcn_mfma_f32_16x16x32_bf16(Afr[mi], Bf, acc[mi][nj], 0, 0, 0);
        }
    }

    // ---- row sums of squares
#pragma unroll
    for (int mi = 0; mi < 4; ++mi)
#pragma unroll
        for (int r = 0; r < 4; ++r) {
            float s = acc[mi][0][r] * acc[mi][0][r] + acc[mi][1][r] * acc[mi][1][r]
                    + acc[mi][2][r] * acc[mi][2][r] + acc[mi][3][r] * acc[mi][3][r];
            s += __shfl_down(s, 8); s += __shfl_down(s, 4);
            s += __shfl_down(s, 2); s += __shfl_down(s, 1);
            if (l15 == 0) rowsq[wu][mi * 16 + quad * 4 + r] = s;
        }
    __syncthreads();
    if (t < 64) {
        float s = 0.f;
#pragma unroll
        for (int w2 = 0; w2 < 8; ++w2) s += rowsq[w2][t];
        invn[t] = 1.f / fmaxf(sqrtf(s), 1e-12f);
    }
    __syncthreads();

    // ---- write normalized Tn bf16 (Pf region dead)
#pragma unroll
    for (int mi = 0; mi < 4; ++mi)
#pragma unroll
        for (int r = 0; r < 4; ++r) {
            int row = mi * 16 + quad * 4 + r;
            if (row < 51) {
                float iv = invn[row];
#pragma unroll
                for (int nj = 0; nj < 4; ++nj)
                    TnBuf[row * 520 + (wu * 4 + nj) * 16 + l15] = f2bf(acc[mi][nj][r] * iv);
            }
        }
    __syncthreads();

    // ---- phase 2: U = Qbb @ Tn^T (A fragments contiguous 1KB)
    const u16* Qbf = Qbbf + (size_t)i * 6 * 16 * 512;
    f32x4 ua[3];
#pragma unroll
    for (int e = 0; e < 3; ++e) ua[e] = (f32x4){0.f, 0.f, 0.f, 0.f};

    if (wu < 6) {
        int mi = wu;
        const u16* Ar = Qbf + (size_t)mi * 16 * 512 + lane * 8;
        bf16x8 Af = ld_bf8(Ar);
        for (int ks = 0; ks < 16; ++ks) {
            bf16x8 An;
            if (ks < 15) An = ld_bf8(Ar + (ks + 1) * 512);
#pragma unroll
            for (int e = 0; e < 3; ++e) {
                bf16x8 Bf = ld_bf8(TnBuf + (e * 16 + l15) * 520 + ks * 32 + quad * 8);
                ua[e] = __builtin_amdgcn_mfma_f32_16x16x32_bf16(Af, Bf, ua[e], 0, 0, 0);
            }
            Af = An;
        }
    } else {
        int w2 = wu - 6;
        int rowB = 48 + l15; if (rowB > 50) rowB = 50;
        const u16* Ar0 = Qbf + (size_t)(3 * w2 + 0) * 16 * 512 + lane * 8;
        const u16* Ar1 = Qbf + (size_t)(3 * w2 + 1) * 16 * 512 + lane * 8;
        const u16* Ar2 = Qbf + (size_t)(3 * w2 + 2) * 16 * 512 + lane * 8;
        bf16x8 Af0 = ld_bf8(Ar0);
        bf16x8 Af1 = ld_bf8(Ar1);
        bf16x8 Af2 = ld_bf8(Ar2);
        for (int ks = 0; ks < 16; ++ks) {
            bf16x8 An0, An1, An2;
            if (ks < 15) {
                An0 = ld_bf8(Ar0 + (ks + 1) * 512);
                An1 = ld_bf8(Ar1 + (ks + 1) * 512);
                An2 = ld_bf8(Ar2 + (ks + 1) * 512);
            }
            bf16x8 Bf = ld_bf8(TnBuf + rowB * 520 + ks * 32 + quad * 8);
            ua[0] = __builtin_amdgcn_mfma_f32_16x16x32_bf16(Af0, Bf, ua[0], 0, 0, 0);
            ua[1] = __builtin_amdgcn_mfma_f32_16x16x32_bf16(Af1, Bf, ua[1], 0, 0, 0);
            ua[2] = __builtin_amdgcn_mfma_f32_16x16x32_bf16(Af2, Bf, ua[2], 0, 0, 0);
            Af0 = An0; Af1 = An1; Af2 = An2;
        }
    }
    __syncthreads();   // Tn reads done before U overwrites

    // ---- write U (96 x 51)
    if (wu < 6) {
#pragma unroll
        for (int e = 0; e < 3; ++e) {
            int l = e * 16 + l15;
            int q0 = wu * 16 + quad * 4;
#pragma unroll
            for (int r = 0; r < 4; ++r) ULDS[(q0 + r) * 52 + l] = ua[e][r];
        }
    } else {
        int l = 48 + l15;
        if (l < 51) {
            int w2 = wu - 6;
#pragma unroll
            for (int e = 0; e < 3; ++e) {
                int q0 = (3 * w2 + e) * 16 + quad * 4;
#pragma unroll
                for (int r = 0; r < 4; ++r) ULDS[(q0 + r) * 52 + l] = ua[e][r];
            }
        }
    }
    __syncthreads();

    // ---- softmax stats, 8 threads per column/row + width-8 butterfly
    float invT = 1.f / temp_p[0];
    if (t < 408) {
        int l = t >> 3, sub = t & 7;
        float vbuf[4]; float mm = -1e30f;
#pragma unroll
        for (int q = 0; q < 4; ++q) {
            float v = ULDS[(32 + sub + 8 * q) * 52 + l] * invT;
            vbuf[q] = v;
            mm = fmaxf(mm, v);
        }
#pragma unroll
        for (int o = 1; o < 8; o <<= 1) mm = fmaxf(mm, __shfl_xor(mm, o, 8));
        float z = 0.f;
#pragma unroll
        for (int q = 0; q < 4; ++q) z += expf(vbuf[q] - mm);
#pragma unroll
        for (int o = 1; o < 8; o <<= 1) z += __shfl_xor(z, o, 8);
        if (sub == 0) { colM[l] = mm; colZ[l] = 1.f / z; }
    }
    if (t < 256) {
        int u = t >> 3, sub = t & 7;
        float vbuf[7]; int cnt = 0; float mm = -1e30f;
        for (int l = sub; l < 51; l += 8) {
            float v = ULDS[(64 + u) * 52 + l] * invT;
            vbuf[cnt++] = v;
            mm = fmaxf(mm, v);
        }
#pragma unroll
        for (int o = 1; o < 8; o <<= 1) mm = fmaxf(mm, __shfl_xor(mm, o, 8));
        float z = 0.f;
        for (int q = 0; q < cnt; ++q) z += expf(vbuf[q] - mm);
#pragma unroll
        for (int o = 1; o < 8; o <<= 1) z += __shfl_xor(z, o, 8);
        if (sub == 0) { rowM[u] = mm; rowZ[u] = 1.f / z; }
    }
    __syncthreads();

    // ---- final reduction
    float part = 0.f;
    for (int f = t; f < LT * 51; f += 512) {
        int u = f / 51, l = f - u * 51;
        float u0 = ULDS[u * 52 + l];
        float c2 = (u0 > 0.f) ? u0 : 0.1f * u0;
        float av = expf(ULDS[(32 + u) * 52 + l] * invT - colM[l]) * colZ[l];
        float bv = expf(ULDS[(64 + u) * 52 + l] * invT - rowM[u]) * rowZ[u];
        part += c2 * (av * (1.f / 51.f) + bv * (1.f / 32.f));
    }
    for (int o = 32; o > 0; o >>= 1) part += __shfl_down(part, o);
    if (lane == 0) redw[wu] = part;
    __syncthreads();
    if (t == 0) {
        float s = 0.f;
#pragma unroll
        for (int w2 = 0; w2 < 8; ++w2) s += redw[w2];
        out[b * NCAP + i] = s;
    }
}

extern "C" void kernel_launch(void* const* d_in, const int* in_sizes, int n_in,
                              void* d_out, int out_size, void* d_ws, size_t ws_size,
                              hipStream_t stream) {
    const float* img        = (const float*)d_in[0];
    const float* cap        = (const float*)d_in[1];
    const float* gamw       = (const float*)d_in[3];
    const float* betw       = (const float*)d_in[4];
    const float* w1         = (const float*)d_in[5];
    const float* b1         = (const float*)d_in[6];
    const float* w2         = (const float*)d_in[7];
    const float* b2         = (const float*)d_in[8];
    const float* aggr_scale = (const float*)d_in[9];
    const float* wi2t       = (const float*)d_in[10];
    const float* bi2t       = (const float*)d_in[11];
    const float* wt2i       = (const float*)d_in[12];
    const float* bt2i       = (const float*)d_in[13];
    const float* temp       = (const float*)d_in[14];
    float* out = (float*)d_out;

    float* ws      = (float*)d_ws;
    float* attn_x  = ws + OFF_ATTNX;
    float* WsM     = ws + OFF_WSMAT;
    u16*   wT      = (u16*)(ws + OFF_WT);
    float* gloT    = ws + OFF_GLOT;
    float* attn_yT = ws + OFF_ATTNYT;
    u16*   imgTf   = (u16*)(ws + OFF_IMGT);
    u16*   Qbbf    = (u16*)(ws + OFF_QBB);
    u16*   Qcap    = (u16*)(ws + OFF_QCAP);

    k_pre<<<dim3(2496), dim3(512), 0, stream>>>(img, cap, wi2t, wt2i, gamw, betw,
                                                w1, b1, w2, b2, aggr_scale,
                                                imgTf, gloT, Qbbf, Qcap, wT,
                                                attn_x, WsM);
    k_mid2<<<dim3(1856), dim3(512), 0, stream>>>(img, wT, bi2t, bt2i, Qcap, Qbbf,
                                                 gloT, attn_yT);
    k_main<<<dim3(NCAP, B), dim3(512), 0, stream>>>(attn_x, attn_yT, WsM, imgTf, Qbbf, temp, out);
}

// Round 15
// 427.394 us; speedup vs baseline: 1.0297x; 1.0297x over previous
//
#include <hip/hip_runtime.h>
#include <math.h>

#define B     64
#define NCAP  64
#define LV    197
#define LT    32
#define C     512
#define NSP   196
#define NKEEP 98
#define HID   102
#define KEEPED 49

// Workspace layout (float element offsets). Total ~79.7 MB (< proven 106.8 MB).
#define OFF_ATTNX   12608                     // B*NSP
#define OFF_WSMAT   25152                     // B*NSP*KEEPED
#define OFF_WT      639808                    // u16 2*512*512 (bf16 wi2t^T / wt2i^T)
#define OFF_GLOT    1688384                   // C*NCAP
#define OFF_ATTNYT  1721152                   // 4096*196 floats (transposed [b][i][s])
#define OFF_IMGT    14164800                  // u16 64*7*32*512 fragment-major imgT
#define OFF_QBB     17834816                  // u16 64*6*16*512 fragment-major Qbb
#define OFF_QCAP    19407680                  // u16 64*32*512 row-major cap rows (qproj input)

typedef unsigned int u32;
typedef unsigned short u16;
typedef __bf16 bf16x8 __attribute__((ext_vector_type(8)));
typedef float f32x4 __attribute__((ext_vector_type(4)));
typedef unsigned int uint4v __attribute__((ext_vector_type(4)));

__device__ __forceinline__ u16 f2bf(float f) {
    u32 u = __builtin_bit_cast(u32, f);
    return (u16)((u + 0x7FFFu + ((u >> 16) & 1u)) >> 16);
}
__device__ __forceinline__ bf16x8 ld_bf8(const u16* p) {
    uint4v v = *reinterpret_cast<const uint4v*>(p);
    return __builtin_bit_cast(bf16x8, v);
}

__device__ __forceinline__ float gelu_exact(float x) {
    return 0.5f * x * (1.f + erff(x * 0.70710678118654752f));
}

// ---------------------------------------------------------------- k_pre (1152 blocks, 256 thr):
// imgt-frag (0..511) | cap_norm (512..1023) | wt (1024..1151)   [round-12 partition, measured best]
__global__ __launch_bounds__(256) void k_pre(const float* __restrict__ img,
                                             const float* __restrict__ cap,
                                             const float* __restrict__ wi2t,
                                             const float* __restrict__ wt2i,
                                             u16* __restrict__ imgTf,
                                             float* __restrict__ gloT,
                                             u16* __restrict__ Qbbf,
                                             u16* __restrict__ Qcap,
                                             u16* __restrict__ wT) {
    int idx = blockIdx.x, t = threadIdx.x;
    __shared__ __align__(16) u16 shb[64 * 224];    // 28 KB union

    if (idx < 512) {
        // ---- imgT fragment-major: tile (ks, ct) holds 1KB: value[lane*8+j] =
        //      bf16(img[b][s = ks*32 + (lane>>4)*8 + j][c = ct*16 + (lane&15)])
        int b = idx >> 3, cg = idx & 7;
        for (int f = t; f < 64 * 27; f += 256) shb[(f / 27) * 224 + 197 + (f % 27)] = 0;
        int cc = t & 63;
        for (int sb = t >> 6; sb < 197; sb += 4) {
            float v = img[((size_t)b * LV + sb) * C + cg * 64 + cc];
            shb[cc * 224 + sb] = f2bf(v);
        }
        __syncthreads();
        const u32* Tu = (const u32*)shb;
        u32* outp = (u32*)imgTf + (size_t)b * 7 * 32 * 256;
        for (int f = t; f < 7 * 4 * 256; f += 256) {
            int ks = f >> 10, rem = f & 1023;
            int ctl = rem >> 8, g = rem & 255;
            int lane_o = g >> 2, j2 = g & 3;
            int quad_o = lane_o >> 4, l15_o = lane_o & 15;
            int ccl = ctl * 16 + l15_o;
            int s = ks * 32 + quad_o * 8 + 2 * j2;
            u32 v = Tu[ccl * 112 + (s >> 1)];
            outp[(size_t)(ks * 32 + cg * 4 + ctl) * 256 + g] = v;
        }
    } else if (idx < 1024) {
        // ---- caption norms, 4 rows/block (wave wv owns row tg*4+wv)
        int e = idx - 512, i = e >> 3, tg = e & 7;
        int lane = t & 63, wv = t >> 6;
        int tt = tg * 4 + wv;
        const float* row = cap + ((size_t)i * LT + tt) * C;
        float v[8]; float ss = 0.f;
#pragma unroll
        for (int q = 0; q < 8; ++q) { v[q] = row[lane + 64 * q]; ss += v[q] * v[q]; }
        for (int o = 32; o > 0; o >>= 1) ss += __shfl_down(ss, o);
        ss = __shfl(ss, 0);
        float inv = 1.f / fmaxf(sqrtf(ss), 1e-12f);
        u16* qrow = Qcap + ((size_t)i * 32 + tt) * C;
        int mi = tt >> 4, l15f = tt & 15;
        u16* qfb = Qbbf + (size_t)(i * 6 + mi) * 16 * 512;
#pragma unroll
        for (int q = 0; q < 8; ++q) {
            float n = v[q] * inv;
            u16 nb = f2bf(n);
            int c = lane + 64 * q;
            qrow[c] = nb;
            int ks = c >> 5, quadf = (c >> 3) & 3, jf = c & 7;
            qfb[(size_t)ks * 512 + (quadf * 16 + l15f) * 8 + jf] = nb;
            if (tt == 0) gloT[c * NCAP + i] = n;
        }
    } else {
        // ---- transpose wi2t/wt2i -> bf16 [j][c], one 64x64 tile per block
        int e = idx - 1024;
        int mat = e >> 6, ty = e & 63, jg = ty >> 3, cg = ty & 7;
        const float* W = mat ? wt2i : wi2t;
        u16 (*tile)[65] = (u16(*)[65])shb;
        for (int f = t; f < 4096; f += 256) {
            int cc2 = f >> 6, jj = f & 63;
            tile[jj][cc2] = f2bf(W[(size_t)(cg * 64 + cc2) * 512 + jg * 64 + jj]);
        }
        __syncthreads();
        for (int f = t; f < 4096; f += 256) {
            int jj = f >> 6, cc2 = f & 63;
            wT[((size_t)mat * 512 + jg * 64 + jj) * 512 + cg * 64 + cc2] = tile[jj][cc2];
        }
    }
}

// ---------------------------------------------------------------- k_mid (3456 blocks, 512 thr):
// qproj (0..255) | img_row (256..1855) | attn_y (1856..3455)   [round-12 partition]
// attn_y reads gloT (written by k_pre) — must stay in the second launch.
__global__ __launch_bounds__(512) void k_mid(const float* __restrict__ img,
                                             const u16* __restrict__ wT,
                                             const float* __restrict__ bi2t,
                                             const float* __restrict__ bt2i,
                                             const u16* __restrict__ Qcap,
                                             u16* __restrict__ Qbbf,
                                             const float* __restrict__ gamw,
                                             const float* __restrict__ betw,
                                             const float* __restrict__ w1,
                                             const float* __restrict__ b1,
                                             const float* __restrict__ w2,
                                             const float* __restrict__ b2,
                                             const float* __restrict__ scale_p,
                                             const float* __restrict__ gloT,
                                             float* __restrict__ attn_x,
                                             float* __restrict__ WsM,
                                             float* __restrict__ attn_yT) {
    int idx = blockIdx.x, t = threadIdx.x;
    __shared__ __align__(16) float shm[4960 + 16];   // ~19.9 KB union

    if (idx < 256) {
        // ---- qi2t/qt2i via MFMA (A/B prefetch); output into fragment-major Qbbf
        int i = idx & 63, p = idx >> 6;
        int lane = t & 63, wu = t >> 6;
        int l15 = lane & 15, quad = lane >> 4;
        int mat = wu >> 2;
        int miq = (wu >> 1) & 1;
        int nh  = wu & 1;
        int ni0 = p * 8 + nh * 4;
        const u16* Arow = Qcap + ((size_t)i * 32 + miq * 16 + l15) * 512;
        const u16* Wm   = wT + (size_t)mat * 512 * 512;
        f32x4 acc[4];
#pragma unroll
        for (int n = 0; n < 4; ++n) acc[n] = (f32x4){0.f, 0.f, 0.f, 0.f};
        bf16x8 A = ld_bf8(Arow + quad * 8);
        bf16x8 Bf[4];
#pragma unroll
        for (int n = 0; n < 4; ++n)
            Bf[n] = ld_bf8(Wm + (size_t)((ni0 + n) * 16 + l15) * 512 + quad * 8);
        for (int ks = 0; ks < 16; ++ks) {
            bf16x8 An; bf16x8 Bn[4];
            if (ks < 15) {
                An = ld_bf8(Arow + (ks + 1) * 32 + quad * 8);
#pragma unroll
                for (int n = 0; n < 4; ++n)
                    Bn[n] = ld_bf8(Wm + (size_t)((ni0 + n) * 16 + l15) * 512 + (ks + 1) * 32 + quad * 8);
            }
#pragma unroll
            for (int n = 0; n < 4; ++n)
                acc[n] = __builtin_amdgcn_mfma_f32_16x16x32_bf16(A, Bf[n], acc[n], 0, 0, 0);
            A = An;
#pragma unroll
            for (int n = 0; n < 4; ++n) Bf[n] = Bn[n];
        }
        const float* bias = mat ? bt2i : bi2t;
#pragma unroll
        for (int n = 0; n < 4; ++n) {
            int j = (ni0 + n) * 16 + l15;
            float bj = bias[j];
            int ksf = j >> 5, quadf = (j >> 3) & 3, jf = j & 7;
#pragma unroll
            for (int r = 0; r < 4; ++r) {
                int q = 32 + mat * 32 + miq * 16 + quad * 4 + r;
                int mi = q >> 4, l15f = q & 15;
                Qbbf[(size_t)((i * 6 + mi) * 16 + ksf) * 512 + (quadf * 16 + l15f) * 8 + jf]
                    = f2bf(acc[n][r] + bj);
            }
        }
    } else if (idx < 1856) {
        // ---- LN -> w1 -> gelu -> w2 + attn_x, 8 rows/block
        int e = idx - 256;
        int b = e / 25, sg = e - b * 25;
        int s0 = sg * 8;
        int R = NSP - s0; if (R > 8) R = 8;
        float (*lnr)[C]   = (float(*)[C])shm;
        float (*HH)[104]  = (float(*)[104])(shm + 4096);
        float (*redm)[4]  = (float(*)[4])(shm + 4928);

        int g = t >> 6, lane = t & 63;
        if (g < R) {
            const float* row = img + ((size_t)b * LV + 1 + s0 + g) * C;
            const float* cls = img + (size_t)b * LV * C;
            float sm = 0.f, ss = 0.f, dd = 0.f, sc = 0.f;
            for (int c = lane; c < C; c += 64) {
                float v = row[c];
                float cv = cls[c];
                sm += v; ss += v * v; dd += v * cv; sc += cv * cv;
                lnr[g][c] = v;
            }
            for (int o = 32; o > 0; o >>= 1) {
                sm += __shfl_down(sm, o);
                ss += __shfl_down(ss, o);
                dd += __shfl_down(dd, o);
                sc += __shfl_down(sc, o);
            }
            if (lane == 0) { redm[g][0] = sm; redm[g][1] = ss; redm[g][2] = dd; redm[g][3] = sc; }
        }
        __syncthreads();
        for (int f = t; f < R * C; f += 512) {
            int rr = f >> 9, c = f & 511;
            float mean = redm[rr][0] * (1.f / C);
            float var  = redm[rr][1] * (1.f / C) - mean * mean;
            float rstd = 1.f / sqrtf(var + 1e-5f);
            lnr[rr][c] = (lnr[rr][c] - mean) * rstd * gamw[c] + betw[c];
        }
        if (t < R) {
            float inv0 = 1.f / fmaxf(sqrtf(redm[t][3]), 1e-12f);
            float invs = 1.f / fmaxf(sqrtf(redm[t][1]), 1e-12f);
            attn_x[b * NSP + s0 + t] = redm[t][2] * inv0 * invs;
        }
        __syncthreads();
        if (t < 408) {
            int rr2 = t / 102;
            int j = t - rr2 * 102;
            int rw0 = rr2 * 2, rw1 = rr2 * 2 + 1;
            float a0 = b1[j], a1 = b1[j];
            for (int c = 0; c < C; ++c) {
                float wv = w1[c * HID + j];
                a0 += lnr[rw0][c] * wv;
                a1 += lnr[rw1][c] * wv;
            }
            if (rw0 < R) HH[rw0][j] = gelu_exact(a0);
            if (rw1 < R) HH[rw1][j] = gelu_exact(a1);
        }
        __syncthreads();
        float scale = scale_p[0];
        if (t < 392) {
            int k = t % 49, rh = t / 49;
            if (rh < R) {
                float a = b2[k];
                for (int h = 0; h < HID; ++h) a += HH[rh][h] * w2[h * 49 + k];
                WsM[((size_t)b * NSP + s0 + rh) * 49 + k] = a * scale;
            }
        }
    } else {
        // ---- attn_y transposed, 8 rows/block, wave w owns row w
        int e = idx - 1856;
        int b = e / 25;
        int s0 = (e - b * 25) * 8;
        int R = NSP - s0; if (R > 8) R = 8;
        float (*xr)[C] = (float(*)[C])shm;
        float* rnorm = shm + 4096;

        for (int f = t; f < R * C; f += 512) {
            int rr = f >> 9, c = f & 511;
            xr[rr][c] = img[((size_t)b * LV + 1 + s0 + rr) * C + c];
        }
        __syncthreads();
        {
            int row = t >> 6, l = t & 63;
            if (row < R) {
                float ss = 0.f;
                for (int c = l; c < C; c += 64) { float v = xr[row][c]; ss += v * v; }
                for (int o = 32; o > 0; o >>= 1) ss += __shfl_down(ss, o);
                if (l == 0) rnorm[row] = 1.f / fmaxf(sqrtf(ss), 1e-12f);
            }
        }
        __syncthreads();
        for (int f = t; f < R * C; f += 512) {
            int rr = f >> 9, c = f & 511;
            xr[rr][c] *= rnorm[rr];
        }
        __syncthreads();
        int i = t & 63, w = t >> 6;
        if (w < R) {
            float a0 = 0.f;
            for (int c4 = 0; c4 < C / 4; ++c4) {
                float g0 = gloT[(c4 * 4 + 0) * NCAP + i];
                float g1 = gloT[(c4 * 4 + 1) * NCAP + i];
                float g2 = gloT[(c4 * 4 + 2) * NCAP + i];
                float g3 = gloT[(c4 * 4 + 3) * NCAP + i];
                float4 x0 = ((const float4*)xr[w])[c4];
                a0 += x0.x * g0 + x0.y * g1 + x0.z * g2 + x0.w * g3;
            }
            attn_yT[((size_t)b * NCAP + i) * NSP + s0 + w] = a0;
        }
    }
}

// ---------------------------------------------------------------- main per-pair kernel: rank + two MFMA GEMMs
__global__ __launch_bounds__(512, 4) void k_main(const float* __restrict__ attn_x,
                                                 const float* __restrict__ attn_yT,
                                                 const float* __restrict__ WsM,
                                                 const u16* __restrict__ imgTf,
                                                 const u16* __restrict__ Qbbf,
                                                 const float* __restrict__ temp_p,
                                                 float* __restrict__ out) {
    int lin = blockIdx.x + NCAP * blockIdx.y;     // XCD swizzle: lin%8 selects b-octet
    int b = (lin & 7) * 8 + ((lin >> 3) & 7);
    int i = lin >> 6;
    int t = threadIdx.x;
    int lane = t & 63, wu = t >> 6;
    int l15 = lane & 15, quad = lane >> 4;

    __shared__ __align__(16) u16 TnBuf[51 * 520];   // aliases Pf(51x232) then ULDS(96x52 f32)
    __shared__ float rowsq[8][64];
    __shared__ float invn[64];
    __shared__ float colM[51], colZ[51], rowM[32], rowZ[32], redw[8];
    __shared__ float scoreS[NSP];
    __shared__ int   keepL[NKEEP];
    __shared__ int   nonL[NKEEP];
    __shared__ float snon[NKEEP];
    __shared__ short rnkH[2][NSP];

    u16*   Pf   = TnBuf;
    float* ULDS = (float*)TnBuf;

    // ---- 1. zero Pf rows 0..50 (16B stores) + load scores
    {
        uint4v* Pfv = (uint4v*)Pf;
        for (int f = t; f < 51 * 232 / 8; f += 512) Pfv[f] = (uint4v){0, 0, 0, 0};
    }
    if (t < NSP)
        scoreS[t] = attn_x[b * NSP + t] + attn_yT[((size_t)b * NCAP + i) * NSP + t];
    __syncthreads();
    // ---- 2. stable-descending rank, split over 392 threads
    if (t < 2 * NSP) {
        int half = (t >= NSP) ? 1 : 0;
        int s = t - half * NSP;
        float sv = scoreS[s];
        int u0 = half * 98, u1 = half ? NSP : 98;
        int r = 0;
        for (int u = u0; u < u1; ++u) {
            float o = scoreS[u];
            r += (o > sv) || (o == sv && u < s);
        }
        rnkH[half][s] = (short)r;
    }
    __syncthreads();
    if (t < NSP) {
        int r = rnkH[0][t] + rnkH[1][t];
        if (r < NKEEP) keepL[r] = t;
        else { nonL[r - NKEEP] = t; snon[r - NKEEP] = scoreS[t]; }
    }
    __syncthreads();
    // ---- 3. scatter P into Pf
    if (t == 0) Pf[0] = 0x3F80;                       // cls one-hot (1.0)
    for (int f = t; f < NKEEP * KEEPED; f += 512) {
        int j = f / KEEPED, k = f - j * KEEPED;
        int s = keepL[j];
        Pf[(1 + k) * 232 + 1 + s] = f2bf(expf(WsM[((size_t)b * NSP + s) * KEEPED + k]));
    }
    if (t < NKEEP) Pf[50 * 232 + 1 + nonL[t]] = f2bf(expf(snon[t]));
    __syncthreads();

    // ---- phase 1: T(51x512) = Pfull @ imgT ; wave w owns ct range [4w, 4w+4)
    const u16* imgTb = imgTf + (size_t)b * 7 * 32 * 512;
    f32x4 acc[4][4];
#pragma unroll
    for (int mi = 0; mi < 4; ++mi)
#pragma unroll
        for (int nj = 0; nj < 4; ++nj) acc[mi][nj] = (f32x4){0.f, 0.f, 0.f, 0.f};

    for (int ks = 0; ks < 7; ++ks) {
        bf16x8 Afr[4];
#pragma unroll
        for (int mi = 0; mi < 4; ++mi)
            Afr[mi] = ld_bf8(Pf + (mi * 16 + l15) * 232 + ks * 32 + quad * 8);
#pragma unroll
        for (int nj = 0; nj < 4; ++nj) {
            bf16x8 Bf = ld_bf8(imgTb + (size_t)(ks * 32 + wu * 4 + nj) * 512 + lane * 8);
#pragma unroll
            for (int mi = 0; mi < 4; ++mi)
                acc[mi][nj] = __builtin_amdgcn_mfma_f32_16x16x32_bf16(Afr[mi], Bf, acc[mi][nj], 0, 0, 0);
        }
    }

    // ---- row sums of squares
#pragma unroll
    for (int mi = 0; mi < 4; ++mi)
#pragma unroll
        for (int r = 0; r < 4; ++r) {
            float s = acc[mi][0][r] * acc[mi][0][r] + acc[mi][1][r] * acc[mi][1][r]
                    + acc[mi][2][r] * acc[mi][2][r] + acc[mi][3][r] * acc[mi][3][r];
            s += __shfl_down(s, 8); s += __shfl_down(s, 4);
            s += __shfl_down(s, 2); s += __shfl_down(s, 1);
            if (l15 == 0) rowsq[wu][mi * 16 + quad * 4 + r] = s;
        }
    __syncthreads();
    if (t < 64) {
        float s = 0.f;
#pragma unroll
        for (int w2 = 0; w2 < 8; ++w2) s += rowsq[w2][t];
        invn[t] = 1.f / fmaxf(sqrtf(s), 1e-12f);
    }
    __syncthreads();

    // ---- write normalized Tn bf16 (Pf region dead)
#pragma unroll
    for (int mi = 0; mi < 4; ++mi)
#pragma unroll
        for (int r = 0; r < 4; ++r) {
            int row = mi * 16 + quad * 4 + r;
            if (row < 51) {
                float iv = invn[row];
#pragma unroll
                for (int nj = 0; nj < 4; ++nj)
                    TnBuf[row * 520 + (wu * 4 + nj) * 16 + l15] = f2bf(acc[mi][nj][r] * iv);
            }
        }
    __syncthreads();

    // ---- phase 2: U = Qbb @ Tn^T (A fragments contiguous 1KB)
    const u16* Qbf = Qbbf + (size_t)i * 6 * 16 * 512;
    f32x4 ua[3];
#pragma unroll
    for (int e = 0; e < 3; ++e) ua[e] = (f32x4){0.f, 0.f, 0.f, 0.f};

    if (wu < 6) {
        int mi = wu;
        const u16* Ar = Qbf + (size_t)mi * 16 * 512 + lane * 8;
        bf16x8 Af = ld_bf8(Ar);
        for (int ks = 0; ks < 16; ++ks) {
            bf16x8 An;
            if (ks < 15) An = ld_bf8(Ar + (ks + 1) * 512);
#pragma unroll
            for (int e = 0; e < 3; ++e) {
                bf16x8 Bf = ld_bf8(TnBuf + (e * 16 + l15) * 520 + ks * 32 + quad * 8);
                ua[e] = __builtin_amdgcn_mfma_f32_16x16x32_bf16(Af, Bf, ua[e], 0, 0, 0);
            }
            Af = An;
        }
    } else {
        int w2 = wu - 6;
        int rowB = 48 + l15; if (rowB > 50) rowB = 50;
        const u16* Ar0 = Qbf + (size_t)(3 * w2 + 0) * 16 * 512 + lane * 8;
        const u16* Ar1 = Qbf + (size_t)(3 * w2 + 1) * 16 * 512 + lane * 8;
        const u16* Ar2 = Qbf + (size_t)(3 * w2 + 2) * 16 * 512 + lane * 8;
        bf16x8 Af0 = ld_bf8(Ar0);
        bf16x8 Af1 = ld_bf8(Ar1);
        bf16x8 Af2 = ld_bf8(Ar2);
        for (int ks = 0; ks < 16; ++ks) {
            bf16x8 An0, An1, An2;
            if (ks < 15) {
                An0 = ld_bf8(Ar0 + (ks + 1) * 512);
                An1 = ld_bf8(Ar1 + (ks + 1) * 512);
                An2 = ld_bf8(Ar2 + (ks + 1) * 512);
            }
            bf16x8 Bf = ld_bf8(TnBuf + rowB * 520 + ks * 32 + quad * 8);
            ua[0] = __builtin_amdgcn_mfma_f32_16x16x32_bf16(Af0, Bf, ua[0], 0, 0, 0);
            ua[1] = __builtin_amdgcn_mfma_f32_16x16x32_bf16(Af1, Bf, ua[1], 0, 0, 0);
            ua[2] = __builtin_amdgcn_mfma_f32_16x16x32_bf16(Af2, Bf, ua[2], 0, 0, 0);
            Af0 = An0; Af1 = An1; Af2 = An2;
        }
    }
    __syncthreads();   // Tn reads done before U overwrites

    // ---- write U (96 x 51)
    if (wu < 6) {
#pragma unroll
        for (int e = 0; e < 3; ++e) {
            int l = e * 16 + l15;
            int q0 = wu * 16 + quad * 4;
#pragma unroll
            for (int r = 0; r < 4; ++r) ULDS[(q0 + r) * 52 + l] = ua[e][r];
        }
    } else {
        int l = 48 + l15;
        if (l < 51) {
            int w2 = wu - 6;
#pragma unroll
            for (int e = 0; e < 3; ++e) {
                int q0 = (3 * w2 + e) * 16 + quad * 4;
#pragma unroll
                for (int r = 0; r < 4; ++r) ULDS[(q0 + r) * 52 + l] = ua[e][r];
            }
        }
    }
    __syncthreads();

    // ---- softmax stats, 8 threads per column/row + width-8 butterfly
    float invT = 1.f / temp_p[0];
    if (t < 408) {
        int l = t >> 3, sub = t & 7;
        float vbuf[4]; float mm = -1e30f;
#pragma unroll
        for (int q = 0; q < 4; ++q) {
            float v = ULDS[(32 + sub + 8 * q) * 52 + l] * invT;
            vbuf[q] = v;
            mm = fmaxf(mm, v);
        }
#pragma unroll
        for (int o = 1; o < 8; o <<= 1) mm = fmaxf(mm, __shfl_xor(mm, o, 8));
        float z = 0.f;
#pragma unroll
        for (int q = 0; q < 4; ++q) z += expf(vbuf[q] - mm);
#pragma unroll
        for (int o = 1; o < 8; o <<= 1) z += __shfl_xor(z, o, 8);
        if (sub == 0) { colM[l] = mm; colZ[l] = 1.f / z; }
    }
    if (t < 256) {
        int u = t >> 3, sub = t & 7;
        float vbuf[7]; int cnt = 0; float mm = -1e30f;
        for (int l = sub; l < 51; l += 8) {
            float v = ULDS[(64 + u) * 52 + l] * invT;
            vbuf[cnt++] = v;
            mm = fmaxf(mm, v);
        }
#pragma unroll
        for (int o = 1; o < 8; o <<= 1) mm = fmaxf(mm, __shfl_xor(mm, o, 8));
        float z = 0.f;
        for (int q = 0; q < cnt; ++q) z += expf(vbuf[q] - mm);
#pragma unroll
        for (int o = 1; o < 8; o <<= 1) z += __shfl_xor(z, o, 8);
        if (sub == 0) { rowM[u] = mm; rowZ[u] = 1.f / z; }
    }
    __syncthreads();

    // ---- final reduction
    float part = 0.f;
    for (int f = t; f < LT * 51; f += 512) {
        int u = f / 51, l = f - u * 51;
        float u0 = ULDS[u * 52 + l];
        float c2 = (u0 > 0.f) ? u0 : 0.1f * u0;
        float av = expf(ULDS[(32 + u) * 52 + l] * invT - colM[l]) * colZ[l];
        float bv = expf(ULDS[(64 + u) * 52 + l] * invT - rowM[u]) * rowZ[u];
        part += c2 * (av * (1.f / 51.f) + bv * (1.f / 32.f));
    }
    for (int o = 32; o > 0; o >>= 1) part += __shfl_down(part, o);
    if (lane == 0) redw[wu] = part;
    __syncthreads();
    if (t == 0) {
        float s = 0.f;
#pragma unroll
        for (int w2 = 0; w2 < 8; ++w2) s += redw[w2];
        out[b * NCAP + i] = s;
    }
}

extern "C" void kernel_launch(void* const* d_in, const int* in_sizes, int n_in,
                              void* d_out, int out_size, void* d_ws, size_t ws_size,
                              hipStream_t stream) {
    const float* img        = (const float*)d_in[0];
    const float* cap        = (const float*)d_in[1];
    const float* gamw       = (const float*)d_in[3];
    const float* betw       = (const float*)d_in[4];
    const float* w1         = (const float*)d_in[5];
    const float* b1         = (const float*)d_in[6];
    const float* w2         = (const float*)d_in[7];
    const float* b2         = (const float*)d_in[8];
    const float* aggr_scale = (const float*)d_in[9];
    const float* wi2t       = (const float*)d_in[10];
    const float* bi2t       = (const float*)d_in[11];
    const float* wt2i       = (const float*)d_in[12];
    const float* bt2i       = (const float*)d_in[13];
    const float* temp       = (const float*)d_in[14];
    float* out = (float*)d_out;

    float* ws      = (float*)d_ws;
    float* attn_x  = ws + OFF_ATTNX;
    float* WsM     = ws + OFF_WSMAT;
    u16*   wT      = (u16*)(ws + OFF_WT);
    float* gloT    = ws + OFF_GLOT;
    float* attn_yT = ws + OFF_ATTNYT;
    u16*   imgTf   = (u16*)(ws + OFF_IMGT);
    u16*   Qbbf    = (u16*)(ws + OFF_QBB);
    u16*   Qcap    = (u16*)(ws + OFF_QCAP);

    k_pre<<<dim3(1152), dim3(256), 0, stream>>>(img, cap, wi2t, wt2i, imgTf, gloT, Qbbf, Qcap, wT);
    k_mid<<<dim3(3456), dim3(512), 0, stream>>>(img, wT, bi2t, bt2i, Qcap, Qbbf, gamw, betw,
                                                w1, b1, w2, b2, aggr_scale, gloT,
                                                attn_x, WsM, attn_yT);
    k_main<<<dim3(NCAP, B), dim3(512), 0, stream>>>(attn_x, attn_yT, WsM, imgTf, Qbbf, temp, out);
}

// Round 16
// 363.972 us; speedup vs baseline: 1.2091x; 1.1743x over previous
//
#include <hip/hip_runtime.h>
#include <math.h>

#define B     64
#define NCAP  64
#define LV    197
#define LT    32
#define C     512
#define NSP   196
#define NKEEP 98
#define HID   102
#define KEEPED 49

// Workspace layout (float element offsets). Total ~79.9 MB (< proven 106.8 MB).
#define OFF_ATTNX   12608                     // B*NSP
#define OFF_WSMAT   25152                     // B*NSP*KEEPED
#define OFF_WT      639808                    // u16 2*512*512 (bf16 wi2t^T / wt2i^T)
#define OFF_GLOT    1688384                   // C*NCAP
#define OFF_ATTNYT  1721152                   // 4096*196 floats (transposed [b][i][s])
#define OFF_IMGT    14164800                  // u16 64*7*32*512 fragment-major imgT
#define OFF_QBB     17834816                  // u16 64*6*16*512 fragment-major Qbb
#define OFF_QCAP    19407680                  // u16 64*32*512 row-major cap rows (qproj input)
#define OFF_W1TF    19931968                  // u16 7*16*512 fragment-major w1^T (N=112 pad, K=512)
#define OFF_W2TF    19960640                  // u16 4*4*512 fragment-major w2^T (N=64 pad, K=128 pad)

typedef unsigned int u32;
typedef unsigned short u16;
typedef __bf16 bf16x8 __attribute__((ext_vector_type(8)));
typedef float f32x4 __attribute__((ext_vector_type(4)));
typedef unsigned int uint4v __attribute__((ext_vector_type(4)));

__device__ __forceinline__ u16 f2bf(float f) {
    u32 u = __builtin_bit_cast(u32, f);
    return (u16)((u + 0x7FFFu + ((u >> 16) & 1u)) >> 16);
}
__device__ __forceinline__ bf16x8 ld_bf8(const u16* p) {
    uint4v v = *reinterpret_cast<const uint4v*>(p);
    return __builtin_bit_cast(bf16x8, v);
}

__device__ __forceinline__ float gelu_exact(float x) {
    return 0.5f * x * (1.f + erff(x * 0.70710678118654752f));
}

// ---------------------------------------------------------------- k_pre (1160 blocks, 256 thr):
// imgt-frag (0..511) | cap_norm (512..1023) | wt (1024..1151) | w1t (1152..1158) | w2t (1159)
__global__ __launch_bounds__(256) void k_pre(const float* __restrict__ img,
                                             const float* __restrict__ cap,
                                             const float* __restrict__ wi2t,
                                             const float* __restrict__ wt2i,
                                             const float* __restrict__ w1,
                                             const float* __restrict__ w2,
                                             u16* __restrict__ imgTf,
                                             float* __restrict__ gloT,
                                             u16* __restrict__ Qbbf,
                                             u16* __restrict__ Qcap,
                                             u16* __restrict__ wT,
                                             u16* __restrict__ w1Tf,
                                             u16* __restrict__ w2Tf) {
    int idx = blockIdx.x, t = threadIdx.x;
    __shared__ __align__(16) u16 shb[64 * 224];    // 28 KB union

    if (idx < 512) {
        // ---- imgT fragment-major
        int b = idx >> 3, cg = idx & 7;
        for (int f = t; f < 64 * 27; f += 256) shb[(f / 27) * 224 + 197 + (f % 27)] = 0;
        int cc = t & 63;
        for (int sb = t >> 6; sb < 197; sb += 4) {
            float v = img[((size_t)b * LV + sb) * C + cg * 64 + cc];
            shb[cc * 224 + sb] = f2bf(v);
        }
        __syncthreads();
        const u32* Tu = (const u32*)shb;
        u32* outp = (u32*)imgTf + (size_t)b * 7 * 32 * 256;
        for (int f = t; f < 7 * 4 * 256; f += 256) {
            int ks = f >> 10, rem = f & 1023;
            int ctl = rem >> 8, g = rem & 255;
            int lane_o = g >> 2, j2 = g & 3;
            int quad_o = lane_o >> 4, l15_o = lane_o & 15;
            int ccl = ctl * 16 + l15_o;
            int s = ks * 32 + quad_o * 8 + 2 * j2;
            u32 v = Tu[ccl * 112 + (s >> 1)];
            outp[(size_t)(ks * 32 + cg * 4 + ctl) * 256 + g] = v;
        }
    } else if (idx < 1024) {
        // ---- caption norms, 4 rows/block
        int e = idx - 512, i = e >> 3, tg = e & 7;
        int lane = t & 63, wv = t >> 6;
        int tt = tg * 4 + wv;
        const float* row = cap + ((size_t)i * LT + tt) * C;
        float v[8]; float ss = 0.f;
#pragma unroll
        for (int q = 0; q < 8; ++q) { v[q] = row[lane + 64 * q]; ss += v[q] * v[q]; }
        for (int o = 32; o > 0; o >>= 1) ss += __shfl_down(ss, o);
        ss = __shfl(ss, 0);
        float inv = 1.f / fmaxf(sqrtf(ss), 1e-12f);
        u16* qrow = Qcap + ((size_t)i * 32 + tt) * C;
        int mi = tt >> 4, l15f = tt & 15;
        u16* qfb = Qbbf + (size_t)(i * 6 + mi) * 16 * 512;
#pragma unroll
        for (int q = 0; q < 8; ++q) {
            float n = v[q] * inv;
            u16 nb = f2bf(n);
            int c = lane + 64 * q;
            qrow[c] = nb;
            int ks = c >> 5, quadf = (c >> 3) & 3, jf = c & 7;
            qfb[(size_t)ks * 512 + (quadf * 16 + l15f) * 8 + jf] = nb;
            if (tt == 0) gloT[c * NCAP + i] = n;
        }
    } else if (idx < 1152) {
        // ---- transpose wi2t/wt2i -> bf16 [j][c], one 64x64 tile per block
        int e = idx - 1024;
        int mat = e >> 6, ty = e & 63, jg = ty >> 3, cg = ty & 7;
        const float* W = mat ? wt2i : wi2t;
        u16 (*tile)[65] = (u16(*)[65])shb;
        for (int f = t; f < 4096; f += 256) {
            int cc2 = f >> 6, jj = f & 63;
            tile[jj][cc2] = f2bf(W[(size_t)(cg * 64 + cc2) * 512 + jg * 64 + jj]);
        }
        __syncthreads();
        for (int f = t; f < 4096; f += 256) {
            int jj = f >> 6, cc2 = f & 63;
            wT[((size_t)mat * 512 + jg * 64 + jj) * 512 + cg * 64 + cc2] = tile[jj][cc2];
        }
    } else if (idx < 1159) {
        // ---- w1^T fragment-major: B[n=j][kk=c] = w1[c][j]; N-tile nt, 16 K-tiles
        int nt = idx - 1152;
        u32* outp = (u32*)w1Tf + (size_t)nt * 16 * 256;
        for (int f = t; f < 16 * 256; f += 256) {
            int ks = f >> 8, g = f & 255;
            int lane_o = g >> 2, j2 = g & 3;
            int l15o = lane_o & 15, quado = lane_o >> 4;
            int kk = ks * 32 + quado * 8 + 2 * j2;
            int n = nt * 16 + l15o;
            u32 lo = 0, hi = 0;
            if (n < HID) {
                lo = f2bf(w1[(size_t)kk * HID + n]);
                hi = f2bf(w1[(size_t)(kk + 1) * HID + n]);
            }
            outp[ks * 256 + g] = lo | (hi << 16);
        }
    } else {
        // ---- w2^T fragment-major: B[n=k][kk=h] = w2[h][k]; tiles [nt2(4)][ks2(4)]
        u32* outp = (u32*)w2Tf;
        for (int f = t; f < 16 * 256; f += 256) {
            int tile = f >> 8, g = f & 255;
            int nt2 = tile >> 2, ks2 = tile & 3;
            int lane_o = g >> 2, j2 = g & 3;
            int l15o = lane_o & 15, quado = lane_o >> 4;
            int kk0 = ks2 * 32 + quado * 8 + 2 * j2;
            int n = nt2 * 16 + l15o;
            u32 lo = 0, hi = 0;
            if (n < KEEPED) {
                if (kk0 < HID)     lo = f2bf(w2[(size_t)kk0 * KEEPED + n]);
                if (kk0 + 1 < HID) hi = f2bf(w2[(size_t)(kk0 + 1) * KEEPED + n]);
            }
            outp[tile * 256 + g] = lo | (hi << 16);
        }
    }
}

// ---------------------------------------------------------------- k_mid (2688 blocks, 512 thr):
// qproj (0..255) | img_row MFMA (256..1087) | attn_y (256+832..2687)
// attn_y reads gloT (written by k_pre) — must stay in this second launch (round-13 race lesson).
__global__ __launch_bounds__(512) void k_mid(const float* __restrict__ img,
                                             const u16* __restrict__ wT,
                                             const float* __restrict__ bi2t,
                                             const float* __restrict__ bt2i,
                                             const u16* __restrict__ Qcap,
                                             u16* __restrict__ Qbbf,
                                             const u16* __restrict__ w1Tf,
                                             const u16* __restrict__ w2Tf,
                                             const float* __restrict__ gamw,
                                             const float* __restrict__ betw,
                                             const float* __restrict__ b1,
                                             const float* __restrict__ b2,
                                             const float* __restrict__ scale_p,
                                             const float* __restrict__ gloT,
                                             float* __restrict__ attn_x,
                                             float* __restrict__ WsM,
                                             float* __restrict__ attn_yT) {
    int idx = blockIdx.x, t = threadIdx.x;
    __shared__ __align__(16) u16 shu[16 * 520 + 16 * 136];   // 37.6 KB union

    if (idx < 256) {
        // ---- qi2t/qt2i via MFMA (A/B prefetch); output into fragment-major Qbbf
        int i = idx & 63, p = idx >> 6;
        int lane = t & 63, wu = t >> 6;
        int l15 = lane & 15, quad = lane >> 4;
        int mat = wu >> 2;
        int miq = (wu >> 1) & 1;
        int nh  = wu & 1;
        int ni0 = p * 8 + nh * 4;
        const u16* Arow = Qcap + ((size_t)i * 32 + miq * 16 + l15) * 512;
        const u16* Wm   = wT + (size_t)mat * 512 * 512;
        f32x4 acc[4];
#pragma unroll
        for (int n = 0; n < 4; ++n) acc[n] = (f32x4){0.f, 0.f, 0.f, 0.f};
        bf16x8 A = ld_bf8(Arow + quad * 8);
        bf16x8 Bf[4];
#pragma unroll
        for (int n = 0; n < 4; ++n)
            Bf[n] = ld_bf8(Wm + (size_t)((ni0 + n) * 16 + l15) * 512 + quad * 8);
        for (int ks = 0; ks < 16; ++ks) {
            bf16x8 An; bf16x8 Bn[4];
            if (ks < 15) {
                An = ld_bf8(Arow + (ks + 1) * 32 + quad * 8);
#pragma unroll
                for (int n = 0; n < 4; ++n)
                    Bn[n] = ld_bf8(Wm + (size_t)((ni0 + n) * 16 + l15) * 512 + (ks + 1) * 32 + quad * 8);
            }
#pragma unroll
            for (int n = 0; n < 4; ++n)
                acc[n] = __builtin_amdgcn_mfma_f32_16x16x32_bf16(A, Bf[n], acc[n], 0, 0, 0);
            A = An;
#pragma unroll
            for (int n = 0; n < 4; ++n) Bf[n] = Bn[n];
        }
        const float* bias = mat ? bt2i : bi2t;
#pragma unroll
        for (int n = 0; n < 4; ++n) {
            int j = (ni0 + n) * 16 + l15;
            float bj = bias[j];
            int ksf = j >> 5, quadf = (j >> 3) & 3, jf = j & 7;
#pragma unroll
            for (int r = 0; r < 4; ++r) {
                int q = 32 + mat * 32 + miq * 16 + quad * 4 + r;
                int mi = q >> 4, l15f = q & 15;
                Qbbf[(size_t)((i * 6 + mi) * 16 + ksf) * 512 + (quadf * 16 + l15f) * 8 + jf]
                    = f2bf(acc[n][r] + bj);
            }
        }
    } else if (idx < 1088) {
        // ---- img_row via MFMA: 16 s-rows/block, LN+attn_x fp32, two bf16 GEMMs
        int e = idx - 256;
        int b = e / 13, sg = e - b * 13;
        int s0 = sg * 16;
        u16* LNb = shu;              // [16][520]
        u16* Hb  = shu + 16 * 520;   // [16][136]
        int lane = t & 63, wu = t >> 6;
        int l15 = lane & 15, quad = lane >> 4;

        // Phase A: wave wu owns rows 2wu, 2wu+1 — stats in registers, attn_x bit-identical fp32
        {
            int rr0 = 2 * wu, rr1 = 2 * wu + 1;
            int sA = s0 + rr0, sB = s0 + rr1;
            int sAc = sA < NSP ? sA : NSP - 1;
            int sBc = sB < NSP ? sB : NSP - 1;
            const float* rowA = img + ((size_t)b * LV + 1 + sAc) * C;
            const float* rowB = img + ((size_t)b * LV + 1 + sBc) * C;
            const float* cls  = img + (size_t)b * LV * C;
            float v0[8], v1[8];
            float sm0 = 0, ss0 = 0, dd0 = 0, sm1 = 0, ss1 = 0, dd1 = 0, sc = 0;
#pragma unroll
            for (int q = 0; q < 8; ++q) {
                int c = lane + 64 * q;
                float cv = cls[c];
                v0[q] = rowA[c]; v1[q] = rowB[c];
                sm0 += v0[q]; ss0 += v0[q] * v0[q]; dd0 += v0[q] * cv;
                sm1 += v1[q]; ss1 += v1[q] * v1[q]; dd1 += v1[q] * cv;
                sc  += cv * cv;
            }
            for (int o = 32; o > 0; o >>= 1) {
                sm0 += __shfl_down(sm0, o); ss0 += __shfl_down(ss0, o); dd0 += __shfl_down(dd0, o);
                sm1 += __shfl_down(sm1, o); ss1 += __shfl_down(ss1, o); dd1 += __shfl_down(dd1, o);
                sc  += __shfl_down(sc, o);
            }
            sm0 = __shfl(sm0, 0); ss0 = __shfl(ss0, 0);
            sm1 = __shfl(sm1, 0); ss1 = __shfl(ss1, 0);
            float mean0 = sm0 * (1.f / C);
            float rstd0 = 1.f / sqrtf(ss0 * (1.f / C) - mean0 * mean0 + 1e-5f);
            float mean1 = sm1 * (1.f / C);
            float rstd1 = 1.f / sqrtf(ss1 * (1.f / C) - mean1 * mean1 + 1e-5f);
            if (lane == 0) {
                float inv0 = 1.f / fmaxf(sqrtf(sc), 1e-12f);
                if (sA < NSP) attn_x[b * NSP + sA] = dd0 * inv0 * (1.f / fmaxf(sqrtf(ss0), 1e-12f));
                if (sB < NSP) attn_x[b * NSP + sB] = dd1 * inv0 * (1.f / fmaxf(sqrtf(ss1), 1e-12f));
            }
#pragma unroll
            for (int q = 0; q < 8; ++q) {
                int c = lane + 64 * q;
                float g = gamw[c], be = betw[c];
                LNb[rr0 * 520 + c] = f2bf((v0[q] - mean0) * rstd0 * g + be);
                LNb[rr1 * 520 + c] = f2bf((v1[q] - mean1) * rstd1 * g + be);
            }
        }
        __syncthreads();
        // GEMM-1: h = ln @ w1 (wave wu<7 owns N-tile wu); wave 7 zeros Hb K-pad cols
        if (wu < 7) {
            const u16* W1b = w1Tf + (size_t)wu * 16 * 512;
            f32x4 h4 = (f32x4){0.f, 0.f, 0.f, 0.f};
            for (int ks = 0; ks < 16; ++ks) {
                bf16x8 A = ld_bf8(LNb + l15 * 520 + ks * 32 + quad * 8);
                bf16x8 Bv = ld_bf8(W1b + ks * 512 + lane * 8);
                h4 = __builtin_amdgcn_mfma_f32_16x16x32_bf16(A, Bv, h4, 0, 0, 0);
            }
            int col = wu * 16 + l15;
            if (col < HID) {
                float bb = b1[col];
#pragma unroll
                for (int r = 0; r < 4; ++r)
                    Hb[(quad * 4 + r) * 136 + col] = f2bf(gelu_exact(h4[r] + bb));
            } else {
#pragma unroll
                for (int r = 0; r < 4; ++r) Hb[(quad * 4 + r) * 136 + col] = 0;
            }
        } else {
            for (int f = lane; f < 16 * 24; f += 64) {
                int row = f / 24, cc = 112 + f % 24;
                Hb[row * 136 + cc] = 0;
            }
        }
        __syncthreads();
        // GEMM-2: Ws = gelu(h) @ w2 (waves 0..3 own N-tiles)
        if (wu < 4) {
            const u16* W2b = w2Tf + (size_t)wu * 4 * 512;
            f32x4 a2 = (f32x4){0.f, 0.f, 0.f, 0.f};
            for (int ks2 = 0; ks2 < 4; ++ks2) {
                bf16x8 A2 = ld_bf8(Hb + l15 * 136 + ks2 * 32 + quad * 8);
                bf16x8 B2 = ld_bf8(W2b + ks2 * 512 + lane * 8);
                a2 = __builtin_amdgcn_mfma_f32_16x16x32_bf16(A2, B2, a2, 0, 0, 0);
            }
            int k = wu * 16 + l15;
            if (k < KEEPED) {
                float scale = scale_p[0], bk = b2[k];
#pragma unroll
                for (int r = 0; r < 4; ++r) {
                    int row = quad * 4 + r;
                    if (s0 + row < NSP)
                        WsM[((size_t)b * NSP + s0 + row) * 49 + k] = (a2[r] + bk) * scale;
                }
            }
        }
    } else {
        // ---- attn_y transposed, 8 rows/block, wave w owns row w (fp32 — score precision)
        int e = idx - 1088;
        int b = e / 25;
        int s0 = (e - b * 25) * 8;
        int R = NSP - s0; if (R > 8) R = 8;
        float (*xr)[C] = (float(*)[C])shu;
        float* rnorm = (float*)shu + 4096;

        for (int f = t; f < R * C; f += 512) {
            int rr = f >> 9, c = f & 511;
            xr[rr][c] = img[((size_t)b * LV + 1 + s0 + rr) * C + c];
        }
        __syncthreads();
        {
            int row = t >> 6, l = t & 63;
            if (row < R) {
                float ss = 0.f;
                for (int c = l; c < C; c += 64) { float v = xr[row][c]; ss += v * v; }
                for (int o = 32; o > 0; o >>= 1) ss += __shfl_down(ss, o);
                if (l == 0) rnorm[row] = 1.f / fmaxf(sqrtf(ss), 1e-12f);
            }
        }
        __syncthreads();
        for (int f = t; f < R * C; f += 512) {
            int rr = f >> 9, c = f & 511;
            xr[rr][c] *= rnorm[rr];
        }
        __syncthreads();
        int i = t & 63, w = t >> 6;
        if (w < R) {
            float a0 = 0.f;
            for (int c4 = 0; c4 < C / 4; ++c4) {
                float g0 = gloT[(c4 * 4 + 0) * NCAP + i];
                float g1 = gloT[(c4 * 4 + 1) * NCAP + i];
                float g2 = gloT[(c4 * 4 + 2) * NCAP + i];
                float g3 = gloT[(c4 * 4 + 3) * NCAP + i];
                float4 x0 = ((const float4*)xr[w])[c4];
                a0 += x0.x * g0 + x0.y * g1 + x0.z * g2 + x0.w * g3;
            }
            attn_yT[((size_t)b * NCAP + i) * NSP + s0 + w] = a0;
        }
    }
}

// ---------------------------------------------------------------- main per-pair kernel: rank + two MFMA GEMMs
__global__ __launch_bounds__(512, 4) void k_main(const float* __restrict__ attn_x,
                                                 const float* __restrict__ attn_yT,
                                                 const float* __restrict__ WsM,
                                                 const u16* __restrict__ imgTf,
                                                 const u16* __restrict__ Qbbf,
                                                 const float* __restrict__ temp_p,
                                                 float* __restrict__ out) {
    int lin = blockIdx.x + NCAP * blockIdx.y;     // XCD swizzle: lin%8 selects b-octet
    int b = (lin & 7) * 8 + ((lin >> 3) & 7);
    int i = lin >> 6;
    int t = threadIdx.x;
    int lane = t & 63, wu = t >> 6;
    int l15 = lane & 15, quad = lane >> 4;

    __shared__ __align__(16) u16 TnBuf[51 * 520];   // aliases Pf(51x232) then ULDS(96x52 f32)
    __shared__ float rowsq[8][64];
    __shared__ float invn[64];
    __shared__ float colM[51], colZ[51], rowM[32], rowZ[32], redw[8];
    __shared__ float scoreS[NSP];
    __shared__ int   keepL[NKEEP];
    __shared__ int   nonL[NKEEP];
    __shared__ float snon[NKEEP];
    __shared__ short rnkH[2][NSP];

    u16*   Pf   = TnBuf;
    float* ULDS = (float*)TnBuf;

    // ---- 1. zero Pf rows 0..50 (16B stores) + load scores
    {
        uint4v* Pfv = (uint4v*)Pf;
        for (int f = t; f < 51 * 232 / 8; f += 512) Pfv[f] = (uint4v){0, 0, 0, 0};
    }
    if (t < NSP)
        scoreS[t] = attn_x[b * NSP + t] + attn_yT[((size_t)b * NCAP + i) * NSP + t];
    __syncthreads();
    // ---- 2. stable-descending rank, split over 392 threads
    if (t < 2 * NSP) {
        int half = (t >= NSP) ? 1 : 0;
        int s = t - half * NSP;
        float sv = scoreS[s];
        int u0 = half * 98, u1 = half ? NSP : 98;
        int r = 0;
        for (int u = u0; u < u1; ++u) {
            float o = scoreS[u];
            r += (o > sv) || (o == sv && u < s);
        }
        rnkH[half][s] = (short)r;
    }
    __syncthreads();
    if (t < NSP) {
        int r = rnkH[0][t] + rnkH[1][t];
        if (r < NKEEP) keepL[r] = t;
        else { nonL[r - NKEEP] = t; snon[r - NKEEP] = scoreS[t]; }
    }
    __syncthreads();
    // ---- 3. scatter P into Pf
    if (t == 0) Pf[0] = 0x3F80;                       // cls one-hot (1.0)
    for (int f = t; f < NKEEP * KEEPED; f += 512) {
        int j = f / KEEPED, k = f - j * KEEPED;
        int s = keepL[j];
        Pf[(1 + k) * 232 + 1 + s] = f2bf(expf(WsM[((size_t)b * NSP + s) * KEEPED + k]));
    }
    if (t < NKEEP) Pf[50 * 232 + 1 + nonL[t]] = f2bf(expf(snon[t]));
    __syncthreads();

    // ---- phase 1: T(51x512) = Pfull @ imgT ; wave w owns ct range [4w, 4w+4)
    const u16* imgTb = imgTf + (size_t)b * 7 * 32 * 512;
    f32x4 acc[4][4];
#pragma unroll
    for (int mi = 0; mi < 4; ++mi)
#pragma unroll
        for (int nj = 0; nj < 4; ++nj) acc[mi][nj] = (f32x4){0.f, 0.f, 0.f, 0.f};

    for (int ks = 0; ks < 7; ++ks) {
        bf16x8 Afr[4];
#pragma unroll
        for (int mi = 0; mi < 4; ++mi)
            Afr[mi] = ld_bf8(Pf + (mi * 16 + l15) * 232 + ks * 32 + quad * 8);
#pragma unroll
        for (int nj = 0; nj < 4; ++nj) {
            bf16x8 Bf = ld_bf8(imgTb + (size_t)(ks * 32 + wu * 4 + nj) * 512 + lane * 8);
#pragma unroll
            for (int mi = 0; mi < 4; ++mi)
                acc[mi][nj] = __builtin_amdgcn_mfma_f32_16x16x32_bf16(Afr[mi], Bf, acc[mi][nj], 0, 0, 0);
        }
    }

    // ---- row sums of squares
#pragma unroll
    for (int mi = 0; mi < 4; ++mi)
#pragma unroll
        for (int r = 0; r < 4; ++r) {
            float s = acc[mi][0][r] * acc[mi][0][r] + acc[mi][1][r] * acc[mi][1][r]
                    + acc[mi][2][r] * acc[mi][2][r] + acc[mi][3][r] * acc[mi][3][r];
            s += __shfl_down(s, 8); s += __shfl_down(s, 4);
            s += __shfl_down(s, 2); s += __shfl_down(s, 1);
            if (l15 == 0) rowsq[wu][mi * 16 + quad * 4 + r] = s;
        }
    __syncthreads();
    if (t < 64) {
        float s = 0.f;
#pragma unroll
        for (int w2 = 0; w2 < 8; ++w2) s += rowsq[w2][t];
        invn[t] = 1.f / fmaxf(sqrtf(s), 1e-12f);
    }
    __syncthreads();

    // ---- write normalized Tn bf16 (Pf region dead)
#pragma unroll
    for (int mi = 0; mi < 4; ++mi)
#pragma unroll
        for (int r = 0; r < 4; ++r) {
            int row = mi * 16 + quad * 4 + r;
            if (row < 51) {
                float iv = invn[row];
#pragma unroll
                for (int nj = 0; nj < 4; ++nj)
                    TnBuf[row * 520 + (wu * 4 + nj) * 16 + l15] = f2bf(acc[mi][nj][r] * iv);
            }
        }
    __syncthreads();

    // ---- phase 2: U = Qbb @ Tn^T (A fragments contiguous 1KB)
    const u16* Qbf = Qbbf + (size_t)i * 6 * 16 * 512;
    f32x4 ua[3];
#pragma unroll
    for (int e = 0; e < 3; ++e) ua[e] = (f32x4){0.f, 0.f, 0.f, 0.f};

    if (wu < 6) {
        int mi = wu;
        const u16* Ar = Qbf + (size_t)mi * 16 * 512 + lane * 8;
        bf16x8 Af = ld_bf8(Ar);
        for (int ks = 0; ks < 16; ++ks) {
            bf16x8 An;
            if (ks < 15) An = ld_bf8(Ar + (ks + 1) * 512);
#pragma unroll
            for (int e = 0; e < 3; ++e) {
                bf16x8 Bf = ld_bf8(TnBuf + (e * 16 + l15) * 520 + ks * 32 + quad * 8);
                ua[e] = __builtin_amdgcn_mfma_f32_16x16x32_bf16(Af, Bf, ua[e], 0, 0, 0);
            }
            Af = An;
        }
    } else {
        int w2 = wu - 6;
        int rowB = 48 + l15; if (rowB > 50) rowB = 50;
        const u16* Ar0 = Qbf + (size_t)(3 * w2 + 0) * 16 * 512 + lane * 8;
        const u16* Ar1 = Qbf + (size_t)(3 * w2 + 1) * 16 * 512 + lane * 8;
        const u16* Ar2 = Qbf + (size_t)(3 * w2 + 2) * 16 * 512 + lane * 8;
        bf16x8 Af0 = ld_bf8(Ar0);
        bf16x8 Af1 = ld_bf8(Ar1);
        bf16x8 Af2 = ld_bf8(Ar2);
        for (int ks = 0; ks < 16; ++ks) {
            bf16x8 An0, An1, An2;
            if (ks < 15) {
                An0 = ld_bf8(Ar0 + (ks + 1) * 512);
                An1 = ld_bf8(Ar1 + (ks + 1) * 512);
                An2 = ld_bf8(Ar2 + (ks + 1) * 512);
            }
            bf16x8 Bf = ld_bf8(TnBuf + rowB * 520 + ks * 32 + quad * 8);
            ua[0] = __builtin_amdgcn_mfma_f32_16x16x32_bf16(Af0, Bf, ua[0], 0, 0, 0);
            ua[1] = __builtin_amdgcn_mfma_f32_16x16x32_bf16(Af1, Bf, ua[1], 0, 0, 0);
            ua[2] = __builtin_amdgcn_mfma_f32_16x16x32_bf16(Af2, Bf, ua[2], 0, 0, 0);
            Af0 = An0; Af1 = An1; Af2 = An2;
        }
    }
    __syncthreads();   // Tn reads done before U overwrites

    // ---- write U (96 x 51)
    if (wu < 6) {
#pragma unroll
        for (int e = 0; e < 3; ++e) {
            int l = e * 16 + l15;
            int q0 = wu * 16 + quad * 4;
#pragma unroll
            for (int r = 0; r < 4; ++r) ULDS[(q0 + r) * 52 + l] = ua[e][r];
        }
    } else {
        int l = 48 + l15;
        if (l < 51) {
            int w2 = wu - 6;
#pragma unroll
            for (int e = 0; e < 3; ++e) {
                int q0 = (3 * w2 + e) * 16 + quad * 4;
#pragma unroll
                for (int r = 0; r < 4; ++r) ULDS[(q0 + r) * 52 + l] = ua[e][r];
            }
        }
    }
    __syncthreads();

    // ---- softmax stats, 8 threads per column/row + width-8 butterfly
    float invT = 1.f / temp_p[0];
    if (t < 408) {
        int l = t >> 3, sub = t & 7;
        float vbuf[4]; float mm = -1e30f;
#pragma unroll
        for (int q = 0; q < 4; ++q) {
            float v = ULDS[(32 + sub + 8 * q) * 52 + l] * invT;
            vbuf[q] = v;
            mm = fmaxf(mm, v);
        }
#pragma unroll
        for (int o = 1; o < 8; o <<= 1) mm = fmaxf(mm, __shfl_xor(mm, o, 8));
        float z = 0.f;
#pragma unroll
        for (int q = 0; q < 4; ++q) z += expf(vbuf[q] - mm);
#pragma unroll
        for (int o = 1; o < 8; o <<= 1) z += __shfl_xor(z, o, 8);
        if (sub == 0) { colM[l] = mm; colZ[l] = 1.f / z; }
    }
    if (t < 256) {
        int u = t >> 3, sub = t & 7;
        float vbuf[7]; int cnt = 0; float mm = -1e30f;
        for (int l = sub; l < 51; l += 8) {
            float v = ULDS[(64 + u) * 52 + l] * invT;
            vbuf[cnt++] = v;
            mm = fmaxf(mm, v);
        }
#pragma unroll
        for (int o = 1; o < 8; o <<= 1) mm = fmaxf(mm, __shfl_xor(mm, o, 8));
        float z = 0.f;
        for (int q = 0; q < cnt; ++q) z += expf(vbuf[q] - mm);
#pragma unroll
        for (int o = 1; o < 8; o <<= 1) z += __shfl_xor(z, o, 8);
        if (sub == 0) { rowM[u] = mm; rowZ[u] = 1.f / z; }
    }
    __syncthreads();

    // ---- final reduction
    float part = 0.f;
    for (int f = t; f < LT * 51; f += 512) {
        int u = f / 51, l = f - u * 51;
        float u0 = ULDS[u * 52 + l];
        float c2 = (u0 > 0.f) ? u0 : 0.1f * u0;
        float av = expf(ULDS[(32 + u) * 52 + l] * invT - colM[l]) * colZ[l];
        float bv = expf(ULDS[(64 + u) * 52 + l] * invT - rowM[u]) * rowZ[u];
        part += c2 * (av * (1.f / 51.f) + bv * (1.f / 32.f));
    }
    for (int o = 32; o > 0; o >>= 1) part += __shfl_down(part, o);
    if (lane == 0) redw[wu] = part;
    __syncthreads();
    if (t == 0) {
        float s = 0.f;
#pragma unroll
        for (int w2 = 0; w2 < 8; ++w2) s += redw[w2];
        out[b * NCAP + i] = s;
    }
}

extern "C" void kernel_launch(void* const* d_in, const int* in_sizes, int n_in,
                              void* d_out, int out_size, void* d_ws, size_t ws_size,
                              hipStream_t stream) {
    const float* img        = (const float*)d_in[0];
    const float* cap        = (const float*)d_in[1];
    const float* gamw       = (const float*)d_in[3];
    const float* betw       = (const float*)d_in[4];
    const float* w1         = (const float*)d_in[5];
    const float* b1         = (const float*)d_in[6];
    const float* w2         = (const float*)d_in[7];
    const float* b2         = (const float*)d_in[8];
    const float* aggr_scale = (const float*)d_in[9];
    const float* wi2t       = (const float*)d_in[10];
    const float* bi2t       = (const float*)d_in[11];
    const float* wt2i       = (const float*)d_in[12];
    const float* bt2i       = (const float*)d_in[13];
    const float* temp       = (const float*)d_in[14];
    float* out = (float*)d_out;

    float* ws      = (float*)d_ws;
    float* attn_x  = ws + OFF_ATTNX;
    float* WsM     = ws + OFF_WSMAT;
    u16*   wT      = (u16*)(ws + OFF_WT);
    float* gloT    = ws + OFF_GLOT;
    float* attn_yT = ws + OFF_ATTNYT;
    u16*   imgTf   = (u16*)(ws + OFF_IMGT);
    u16*   Qbbf    = (u16*)(ws + OFF_QBB);
    u16*   Qcap    = (u16*)(ws + OFF_QCAP);
    u16*   w1Tf    = (u16*)(ws + OFF_W1TF);
    u16*   w2Tf    = (u16*)(ws + OFF_W2TF);

    k_pre<<<dim3(1160), dim3(256), 0, stream>>>(img, cap, wi2t, wt2i, w1, w2,
                                                imgTf, gloT, Qbbf, Qcap, wT, w1Tf, w2Tf);
    k_mid<<<dim3(2688), dim3(512), 0, stream>>>(img, wT, bi2t, bt2i, Qcap, Qbbf,
                                                w1Tf, w2Tf, gamw, betw, b1, b2, aggr_scale,
                                                gloT, attn_x, WsM, attn_yT);
    k_main<<<dim3(NCAP, B), dim3(512), 0, stream>>>(attn_x, attn_yT, WsM, imgTf, Qbbf, temp, out);
}